// Round 1
// baseline (325.393 us; speedup 1.0000x reference)
//
#include <hip/hip_runtime.h>
#include <math.h>

// symLoss: S=3 sym candidates, B=512, N=1000 samples, G=32 grid.
// out[0] = mean over (s,b) of sum_n || (reflect(p) - cp[lin]) * (1 - v[lin]) ||
// out[1] = same with quaternion rotation.
// One block per (b, s); each block computes BOTH losses for its pair
// (shares the surfaceSamples reads). Block-reduce, then one atomicAdd
// per output per block with the 1/(S*B) scale folded in.

#define GRID_N   32
#define NGRID3   32768            // 32^3
#define GRID_MIN_F (-0.484375f)   // -0.5 + 0.5/32

__device__ __forceinline__ float point_loss(float x, float y, float z,
                                            const float* __restrict__ vol,
                                            const float* __restrict__ cp)
{
    // voxel index: clip then round (jnp.round = nearest-even = rintf)
    float fx = fminf(fmaxf((x - GRID_MIN_F) * 32.0f, 0.0f), 31.0f);
    float fy = fminf(fmaxf((y - GRID_MIN_F) * 32.0f, 0.0f), 31.0f);
    float fz = fminf(fmaxf((z - GRID_MIN_F) * 32.0f, 0.0f), 31.0f);
    int ix = (int)rintf(fx);
    int iy = (int)rintf(fy);
    int iz = (int)rintf(fz);
    int lin = ix * 1024 + iy * 32 + iz;

    float m  = 1.0f - vol[lin];
    float dx = (x - cp[lin * 3 + 0]) * m;
    float dy = (y - cp[lin * 3 + 1]) * m;
    float dz = (z - cp[lin * 3 + 2]) * m;
    float n2 = dx * dx + dy * dy + dz * dz;
    return sqrtf(fmaxf(n2, 1e-30f));
}

__global__ __launch_bounds__(256) void symloss_kernel(
    const float* __restrict__ planes,   // (S,B,4)
    const float* __restrict__ quats,    // (S,B,4)
    const float* __restrict__ cps,      // (B, 32768*3)
    const float* __restrict__ samples,  // (B,N,3)
    const float* __restrict__ volume,   // (B, 32768)
    float* __restrict__ out,            // 2 floats
    int S, int B, int N)
{
    const int b = blockIdx.x;
    const int s = blockIdx.y;

    const float* __restrict__ sp  = samples + (size_t)b * N * 3;
    const float* __restrict__ vol = volume  + (size_t)b * NGRID3;
    const float* __restrict__ cp  = cps     + (size_t)b * NGRID3 * 3;

    // per-(s,b) params — 16B aligned, broadcast via cache
    const float4 pl = ((const float4*)planes)[(size_t)s * B + b];
    const float4 q  = ((const float4*)quats )[(size_t)s * B + b];

    const float n2pl    = pl.x * pl.x + pl.y * pl.y + pl.z * pl.z;
    const float inv_n2  = 1.0f / (n2pl + 1e-8f);

    const float qw = q.x, qx = q.y, qy = q.z, qz = q.w;
    const float w2mu = qw * qw - (qx * qx + qy * qy + qz * qz);

    float sum_p = 0.0f, sum_q = 0.0f;

    for (int n = threadIdx.x; n < N; n += blockDim.x) {
        const float px = sp[n * 3 + 0];
        const float py = sp[n * 3 + 1];
        const float pz = sp[n * 3 + 2];

        // ---- plane reflection: p - 2*(p.n + d) * n / (|n|^2 + 1e-8)
        {
            float len = 2.0f * (px * pl.x + py * pl.y + pz * pl.z + pl.w);
            float f   = len * inv_n2;
            float ax  = px - f * pl.x;
            float ay  = py - f * pl.y;
            float az  = pz - f * pl.z;
            sum_p += point_loss(ax, ay, az, vol, cp);
        }

        // ---- quaternion rotate (unnormalized q, matches q*(0,p)*conj(q)):
        // v' = (w^2 - |u|^2) p + 2(u.p) u + 2w (u x p)
        {
            float udp = qx * px + qy * py + qz * pz;
            float cx  = qy * pz - qz * py;
            float cy  = qz * px - qx * pz;
            float cz  = qx * py - qy * px;
            float bx  = w2mu * px + 2.0f * udp * qx + 2.0f * qw * cx;
            float by  = w2mu * py + 2.0f * udp * qy + 2.0f * qw * cy;
            float bz  = w2mu * pz + 2.0f * udp * qz + 2.0f * qw * cz;
            sum_q += point_loss(bx, by, bz, vol, cp);
        }
    }

    // ---- block reduction: wave shuffle (64-wide) then LDS across 4 waves
    for (int off = 32; off > 0; off >>= 1) {
        sum_p += __shfl_down(sum_p, off);
        sum_q += __shfl_down(sum_q, off);
    }

    __shared__ float red[8][2];   // up to 8 waves
    const int lane = threadIdx.x & 63;
    const int wid  = threadIdx.x >> 6;
    if (lane == 0) { red[wid][0] = sum_p; red[wid][1] = sum_q; }
    __syncthreads();

    if (threadIdx.x == 0) {
        const int nwaves = (blockDim.x + 63) >> 6;
        float tp = 0.0f, tq = 0.0f;
        for (int w = 0; w < nwaves; ++w) { tp += red[w][0]; tq += red[w][1]; }
        const float scale = 1.0f / (float)(S * B);
        atomicAdd(&out[0], tp * scale);
        atomicAdd(&out[1], tq * scale);
    }
}

extern "C" void kernel_launch(void* const* d_in, const int* in_sizes, int n_in,
                              void* d_out, int out_size, void* d_ws, size_t ws_size,
                              hipStream_t stream)
{
    const float* planes  = (const float*)d_in[0];  // (S,B,4)
    const float* quats   = (const float*)d_in[1];  // (S,B,4)
    const float* cps     = (const float*)d_in[2];  // (B, G^3*3)
    const float* samples = (const float*)d_in[3];  // (B,N,3)
    const float* volume  = (const float*)d_in[4];  // (B,1,G,G,G)
    float* out = (float*)d_out;

    const int B = in_sizes[4] / NGRID3;        // 512
    const int S = in_sizes[0] / (B * 4);       // 3
    const int N = in_sizes[3] / (B * 3);       // 1000

    // d_out is poisoned to 0xAA before every timed launch — zero it.
    hipMemsetAsync(d_out, 0, 2 * sizeof(float), stream);

    dim3 grid(B, S);
    symloss_kernel<<<grid, 256, 0, stream>>>(planes, quats, cps, samples,
                                             volume, out, S, B, N);
}

// Round 2
// 307.035 us; speedup vs baseline: 1.0598x; 1.0598x over previous
//
#include <hip/hip_runtime.h>
#include <math.h>

// symLoss fused: one block per batch b, all S sym candidates in-block.
// - samples staged to LDS with coalesced float4 loads (read once, not S times)
// - S compile-time-unrolled: per point, 2*S evals => 4*S scattered gathers in
//   flight per loop iteration (latency hiding for the L1/L2-served gathers)
// - block reduce, one scaled atomicAdd per output per block.

#define NGRID3     32768            // 32^3
#define GRID_MIN_F (-0.484375f)     // -0.5 + 0.5/32
#define NTHREADS   256

__device__ __forceinline__ float point_loss(float x, float y, float z,
                                            const float* __restrict__ vol,
                                            const float* __restrict__ cp)
{
    // jnp: clip to [0,31] then round (nearest-even) => rintf after clamp
    float fx = fminf(fmaxf((x - GRID_MIN_F) * 32.0f, 0.0f), 31.0f);
    float fy = fminf(fmaxf((y - GRID_MIN_F) * 32.0f, 0.0f), 31.0f);
    float fz = fminf(fmaxf((z - GRID_MIN_F) * 32.0f, 0.0f), 31.0f);
    int lin = ((int)rintf(fx)) * 1024 + ((int)rintf(fy)) * 32 + (int)rintf(fz);

    float m  = 1.0f - vol[lin];
    float dx = (x - cp[lin * 3 + 0]) * m;
    float dy = (y - cp[lin * 3 + 1]) * m;
    float dz = (z - cp[lin * 3 + 2]) * m;
    return sqrtf(fmaxf(dx * dx + dy * dy + dz * dz, 1e-30f));
}

template <int S>
__global__ __launch_bounds__(NTHREADS) void symloss_fused(
    const float* __restrict__ planes,   // (S,B,4)
    const float* __restrict__ quats,    // (S,B,4)
    const float* __restrict__ cps,      // (B, 32768*3)
    const float* __restrict__ samples,  // (B,N,3)
    const float* __restrict__ volume,   // (B, 32768)
    float* __restrict__ out,            // 2 floats
    int B, int N, float scale)
{
    const int b = blockIdx.x;
    const float* __restrict__ vol = volume + (size_t)b * NGRID3;
    const float* __restrict__ cp  = cps    + (size_t)b * NGRID3 * 3;

    extern __shared__ float spts[];     // N*3 floats
    {
        const float* sp = samples + (size_t)b * N * 3;
        const int n4 = (N * 3) / 4;     // base offset b*N*3*4B: 16B-aligned for N%4==0*3... N*3*4=12000B, ok
        const float4* src = (const float4*)sp;
        float4* dst = (float4*)spts;
        for (int i = threadIdx.x; i < n4; i += NTHREADS) dst[i] = src[i];
        for (int i = n4 * 4 + threadIdx.x; i < N * 3; i += NTHREADS) spts[i] = sp[i];
    }

    // per-s transform params in registers (S is compile-time)
    float plx[S], ply[S], plz[S], plw[S], inv_n2[S];
    float qw[S], qx[S], qy[S], qz[S], w2mu[S];
#pragma unroll
    for (int s = 0; s < S; ++s) {
        float4 pl = ((const float4*)planes)[(size_t)s * B + b];
        float4 q  = ((const float4*)quats )[(size_t)s * B + b];
        plx[s] = pl.x; ply[s] = pl.y; plz[s] = pl.z; plw[s] = pl.w;
        inv_n2[s] = 1.0f / (pl.x * pl.x + pl.y * pl.y + pl.z * pl.z + 1e-8f);
        qw[s] = q.x; qx[s] = q.y; qy[s] = q.z; qz[s] = q.w;
        w2mu[s] = q.x * q.x - (q.y * q.y + q.z * q.z + q.w * q.w);
    }

    __syncthreads();

    float sum_p = 0.0f, sum_q = 0.0f;
    for (int n = threadIdx.x; n < N; n += NTHREADS) {
        const float px = spts[n * 3 + 0];
        const float py = spts[n * 3 + 1];
        const float pz = spts[n * 3 + 2];
#pragma unroll
        for (int s = 0; s < S; ++s) {
            // plane reflection
            float f = 2.0f * (px * plx[s] + py * ply[s] + pz * plz[s] + plw[s]) * inv_n2[s];
            sum_p += point_loss(px - f * plx[s], py - f * ply[s], pz - f * plz[s], vol, cp);

            // quaternion rotate (unnormalized): (w^2-|u|^2)p + 2(u.p)u + 2w(u x p)
            float udp = qx[s] * px + qy[s] * py + qz[s] * pz;
            float cx  = qy[s] * pz - qz[s] * py;
            float cy  = qz[s] * px - qx[s] * pz;
            float cz  = qx[s] * py - qy[s] * px;
            sum_q += point_loss(w2mu[s] * px + 2.0f * (udp * qx[s] + qw[s] * cx),
                                w2mu[s] * py + 2.0f * (udp * qy[s] + qw[s] * cy),
                                w2mu[s] * pz + 2.0f * (udp * qz[s] + qw[s] * cz),
                                vol, cp);
        }
    }

    // wave shuffle reduce (64-wide) then LDS across 4 waves
    for (int off = 32; off > 0; off >>= 1) {
        sum_p += __shfl_down(sum_p, off);
        sum_q += __shfl_down(sum_q, off);
    }
    __shared__ float red[NTHREADS / 64][2];
    const int lane = threadIdx.x & 63;
    const int wid  = threadIdx.x >> 6;
    if (lane == 0) { red[wid][0] = sum_p; red[wid][1] = sum_q; }
    __syncthreads();

    if (threadIdx.x == 0) {
        float tp = 0.0f, tq = 0.0f;
        for (int w = 0; w < NTHREADS / 64; ++w) { tp += red[w][0]; tq += red[w][1]; }
        atomicAdd(&out[0], tp * scale);
        atomicAdd(&out[1], tq * scale);
    }
}

extern "C" void kernel_launch(void* const* d_in, const int* in_sizes, int n_in,
                              void* d_out, int out_size, void* d_ws, size_t ws_size,
                              hipStream_t stream)
{
    const float* planes  = (const float*)d_in[0];
    const float* quats   = (const float*)d_in[1];
    const float* cps     = (const float*)d_in[2];
    const float* samples = (const float*)d_in[3];
    const float* volume  = (const float*)d_in[4];
    float* out = (float*)d_out;

    const int B = in_sizes[4] / NGRID3;     // 512
    const int S = in_sizes[0] / (B * 4);    // 3
    const int N = in_sizes[3] / (B * 3);    // 1000
    const float scale = 1.0f / (float)(S * B);
    const size_t lds = (size_t)N * 3 * sizeof(float);

    hipMemsetAsync(d_out, 0, 2 * sizeof(float), stream);

    switch (S) {
    case 1: symloss_fused<1><<<B, NTHREADS, lds, stream>>>(planes, quats, cps, samples, volume, out, B, N, scale); break;
    case 2: symloss_fused<2><<<B, NTHREADS, lds, stream>>>(planes, quats, cps, samples, volume, out, B, N, scale); break;
    case 3: symloss_fused<3><<<B, NTHREADS, lds, stream>>>(planes, quats, cps, samples, volume, out, B, N, scale); break;
    case 4: symloss_fused<4><<<B, NTHREADS, lds, stream>>>(planes, quats, cps, samples, volume, out, B, N, scale); break;
    default:
        for (int s = 0; s < S; ++s)
            symloss_fused<1><<<B, NTHREADS, lds, stream>>>(planes + (size_t)s * B * 4,
                                                           quats  + (size_t)s * B * 4,
                                                           cps, samples, volume, out, B, N, scale);
        break;
    }
}